// Round 4
// baseline (111.256 us; speedup 1.0000x reference)
//
#include <hip/hip_runtime.h>

#define N_NODES 100000
#define DEG 16
#define N_EDGES (N_NODES * DEG)
#define NT 64                              // nodes per fused block
#define NBLK2 ((N_NODES + NT - 1) / NT)    // 1563 blocks

#define FS 68            // padded LDS row stride (floats): 16B-aligned, <=2-way banks
#define OFF_FEAT 0       // feat_s[81][FS] = 5508 floats; a_s[64][FS] overlays after use
#define OFF_WS   5508    // ws[32][64] = 2048 floats; red[256] (doubles) overlays later
#define OFF_BS   7556    // b_s[80][FS] = 5440 floats
#define OFF_WV   12996   // wv_s[64]
#define OFF_W1   13060   // w1_s[64]
#define OFF_B0   13124   // b0_s[64]
#define SM_TOT   13188   // 52752 B -> 3 blocks/CU

// ---------------------------------------------------------------------------
// Prep: w0T[k][o] = A/B-split transpose of w0 (matches round-2 ws[] layout):
//   o <  64 : w0[o][k]        (A-part: weight for hidden o, input k)
//   o >= 64 : w0[o-64][64+k]  (B-part: weight for hidden o-64, input 64+k)
// 32 KB, L2-resident.  (Round-3 bug was reading w0 rows 64..127 — OOB.)
// ---------------------------------------------------------------------------
__global__ __launch_bounds__(256) void k_prep(const float* __restrict__ w0,
                                              float* __restrict__ w0T) {
    int id = blockIdx.x * 256 + threadIdx.x;
    if (id < 64 * 128) {
        int k = id >> 7, o = id & 127;
        w0T[k * 128 + o] = (o < 64) ? w0[o * 129 + k]
                                    : w0[(o - 64) * 129 + 64 + k];
    }
}

// ---------------------------------------------------------------------------
// Fused: per block of 64 nodes, compute A rows n0..n0+63 (+b0) and B rows
// n0+1..n0+80 (mod N) in LDS from staged feat, then the edge combine.
// Every fma chain is bit-identical to round 2 (k-ascending, bias after).
// ---------------------------------------------------------------------------
__global__ __launch_bounds__(256) void k_fused(const float* __restrict__ feat,
                                               const float* __restrict__ values,
                                               const int* __restrict__ indices,
                                               const float* __restrict__ w0,
                                               const float* __restrict__ w0T,
                                               const float* __restrict__ b0,
                                               const float* __restrict__ w1,
                                               const float* __restrict__ b1,
                                               float* __restrict__ z,
                                               double* __restrict__ partial) {
    __shared__ float smem[SM_TOT];
    float* fs   = smem + OFF_FEAT;   // [81][FS]
    float* wsm  = smem + OFF_WS;     // [32][64]
    float* bsm  = smem + OFF_BS;     // [80][FS]
    float* a_s  = smem + OFF_FEAT;   // overlay, [64][FS]
    float* wv_s = smem + OFF_WV;
    float* w1_s = smem + OFF_W1;
    float* b0_s = smem + OFF_B0;

    const int t  = threadIdx.x;
    const int n0 = blockIdx.x * NT;
    const int nvalid = min(NT, N_NODES - n0);

    if (t < 64) {
        wv_s[t] = w0[t * 129 + 128];
        w1_s[t] = w1[t];
        b0_s[t] = b0[t];
    }
    // stage feat rows n0..n0+80 (mod N), coalesced float4
    for (int idx = t; idx < 81 * 16; idx += 256) {
        int r = idx >> 4, k4 = idx & 15;
        int node = n0 + r;
        if (node >= N_NODES) node -= N_NODES;
        *(float4*)&fs[r * FS + k4 * 4] =
            *(const float4*)&feat[(size_t)node * 64 + k4 * 4];
    }
    // stage ws: B columns, k-half 0
    for (int idx = t; idx < 512; idx += 256) {
        int k = idx >> 4, o4 = idx & 15;
        *(float4*)&wsm[k * 64 + o4 * 4] =
            *(const float4*)&w0T[k * 128 + 64 + o4 * 4];
    }
    __syncthreads();

    const int to = t & 15;   // out4-group: outs to*4..to*4+3
    const int tn = t >> 4;   // row group

// one k-half of the matvec: NR rows per thread, fma chain k-ascending
#define FMA16(ACCR, F4)                                   \
    ACCR[0] = fmaf(F4.x, w40.x, ACCR[0]);                 \
    ACCR[1] = fmaf(F4.x, w40.y, ACCR[1]);                 \
    ACCR[2] = fmaf(F4.x, w40.z, ACCR[2]);                 \
    ACCR[3] = fmaf(F4.x, w40.w, ACCR[3]);                 \
    ACCR[0] = fmaf(F4.y, w41.x, ACCR[0]);                 \
    ACCR[1] = fmaf(F4.y, w41.y, ACCR[1]);                 \
    ACCR[2] = fmaf(F4.y, w41.z, ACCR[2]);                 \
    ACCR[3] = fmaf(F4.y, w41.w, ACCR[3]);                 \
    ACCR[0] = fmaf(F4.z, w42.x, ACCR[0]);                 \
    ACCR[1] = fmaf(F4.z, w42.y, ACCR[1]);                 \
    ACCR[2] = fmaf(F4.z, w42.z, ACCR[2]);                 \
    ACCR[3] = fmaf(F4.z, w42.w, ACCR[3]);                 \
    ACCR[0] = fmaf(F4.w, w43.x, ACCR[0]);                 \
    ACCR[1] = fmaf(F4.w, w43.y, ACCR[1]);                 \
    ACCR[2] = fmaf(F4.w, w43.z, ACCR[2]);                 \
    ACCR[3] = fmaf(F4.w, w43.w, ACCR[3]);

    // ---------------- B-part: 80 rows (fs rows +1), 5 rows/thread -----------
    float accB[5][4];
#pragma unroll
    for (int rr = 0; rr < 5; ++rr) {
        accB[rr][0] = 0.f; accB[rr][1] = 0.f; accB[rr][2] = 0.f; accB[rr][3] = 0.f;
    }
#pragma unroll 1
    for (int h = 0; h < 2; ++h) {
        if (h == 1) {                        // restage ws: B cols, k-half 1
            __syncthreads();
            for (int idx = t; idx < 512; idx += 256) {
                int k = idx >> 4, o4 = idx & 15;
                *(float4*)&wsm[k * 64 + o4 * 4] =
                    *(const float4*)&w0T[(32 + k) * 128 + 64 + o4 * 4];
            }
            __syncthreads();
        }
#pragma unroll
        for (int k4 = 0; k4 < 8; ++k4) {
            const int kk = k4 * 4;
            float4 w40 = *(const float4*)&wsm[(kk + 0) * 64 + to * 4];
            float4 w41 = *(const float4*)&wsm[(kk + 1) * 64 + to * 4];
            float4 w42 = *(const float4*)&wsm[(kk + 2) * 64 + to * 4];
            float4 w43 = *(const float4*)&wsm[(kk + 3) * 64 + to * 4];
#pragma unroll
            for (int rr = 0; rr < 5; ++rr) {
                float4 f4 = *(const float4*)&fs[(tn * 5 + rr + 1) * FS + h * 32 + kk];
                FMA16(accB[rr], f4)
            }
        }
    }
    __syncthreads();
    // write b_s; stage ws: A cols, k-half 0
#pragma unroll
    for (int rr = 0; rr < 5; ++rr) {
        float4 o4v = make_float4(accB[rr][0], accB[rr][1], accB[rr][2], accB[rr][3]);
        *(float4*)&bsm[(tn * 5 + rr) * FS + to * 4] = o4v;
    }
    for (int idx = t; idx < 512; idx += 256) {
        int k = idx >> 4, o4 = idx & 15;
        *(float4*)&wsm[k * 64 + o4 * 4] =
            *(const float4*)&w0T[k * 128 + o4 * 4];
    }
    __syncthreads();

    // ---------------- A-part: 64 rows, 4 rows/thread -------------------------
    float accA[4][4];
#pragma unroll
    for (int rr = 0; rr < 4; ++rr) {
        accA[rr][0] = 0.f; accA[rr][1] = 0.f; accA[rr][2] = 0.f; accA[rr][3] = 0.f;
    }
#pragma unroll 1
    for (int h = 0; h < 2; ++h) {
        if (h == 1) {                        // restage ws: A cols, k-half 1
            __syncthreads();
            for (int idx = t; idx < 512; idx += 256) {
                int k = idx >> 4, o4 = idx & 15;
                *(float4*)&wsm[k * 64 + o4 * 4] =
                    *(const float4*)&w0T[(32 + k) * 128 + o4 * 4];
            }
            __syncthreads();
        }
#pragma unroll
        for (int k4 = 0; k4 < 8; ++k4) {
            const int kk = k4 * 4;
            float4 w40 = *(const float4*)&wsm[(kk + 0) * 64 + to * 4];
            float4 w41 = *(const float4*)&wsm[(kk + 1) * 64 + to * 4];
            float4 w42 = *(const float4*)&wsm[(kk + 2) * 64 + to * 4];
            float4 w43 = *(const float4*)&wsm[(kk + 3) * 64 + to * 4];
#pragma unroll
            for (int rr = 0; rr < 4; ++rr) {
                float4 f4 = *(const float4*)&fs[(tn * 4 + rr) * FS + h * 32 + kk];
                FMA16(accA[rr], f4)
            }
        }
    }
    __syncthreads();   // all feat reads done -> safe to overlay a_s
    {
        float4 bb = *(const float4*)&b0_s[to * 4];
#pragma unroll
        for (int rr = 0; rr < 4; ++rr) {
            float4 o4v = make_float4(accA[rr][0] + bb.x, accA[rr][1] + bb.y,
                                     accA[rr][2] + bb.z, accA[rr][3] + bb.w);
            *(float4*)&a_s[(tn * 4 + rr) * FS + to * 4] = o4v;
        }
    }
    __syncthreads();

    // ---------------- edge combine (round-2 chain, bit-identical) ------------
    const int row = t >> 2;
    double ss = 0.0;
    if (row < nvalid) {
        const int ebase = n0 * 16 + (t << 2);
        int4   c4 = *(const int4*)(indices + N_EDGES + ebase);
        float4 v4 = *(const float4*)(values + ebase);
        int   cols[4] = {c4.x, c4.y, c4.z, c4.w};
        float vv[4]   = {v4.x, v4.y, v4.z, v4.w};
        int   ii[4];
        bool  fb[4];
        bool  anyfb = false;
#pragma unroll
        for (int k = 0; k < 4; ++k) {
            int i = cols[k] - (n0 + 1);
            if (i < 0) i += N_NODES;
            fb[k] = (i >= 80);
            anyfb |= fb[k];
            ii[k] = fb[k] ? 0 : i;
        }
        float acc[4] = {0.f, 0.f, 0.f, 0.f};
#pragma unroll
        for (int q = 0; q < 16; ++q) {
            float4 a4  = *(const float4*)&a_s[row * FS + q * 4];
            float4 wv4 = *(const float4*)&wv_s[q * 4];
            float4 w14 = *(const float4*)&w1_s[q * 4];
#pragma unroll
            for (int k = 0; k < 4; ++k) {
                float4 b4 = *(const float4*)&bsm[ii[k] * FS + q * 4];
                float t0 = fmaf(wv4.x, vv[k], a4.x + b4.x);
                float t1 = fmaf(wv4.y, vv[k], a4.y + b4.y);
                float t2 = fmaf(wv4.z, vv[k], a4.z + b4.z);
                float t3 = fmaf(wv4.w, vv[k], a4.w + b4.w);
                acc[k] = fmaf(w14.x, fmaxf(t0, 0.f), acc[k]);
                acc[k] = fmaf(w14.y, fmaxf(t1, 0.f), acc[k]);
                acc[k] = fmaf(w14.z, fmaxf(t2, 0.f), acc[k]);
                acc[k] = fmaf(w14.w, fmaxf(t3, 0.f), acc[k]);
            }
        }
        if (anyfb) {   // dead for this graph (i = row + j - 1 <= 78 < 80); safety net
#pragma unroll 1
            for (int k = 0; k < 4; ++k) {
                if (fb[k]) {
                    const float* fcol = feat + (size_t)cols[k] * 64;
                    float a = 0.f;
                    for (int hh = 0; hh < 64; ++hh) {
                        float bh = 0.f;
                        for (int kk2 = 0; kk2 < 64; ++kk2)
                            bh = fmaf(fcol[kk2], w0T[kk2 * 128 + 64 + hh], bh);
                        float th = fmaf(wv_s[hh], vv[k], a_s[row * FS + hh] + bh);
                        a = fmaf(w1_s[hh], fmaxf(th, 0.f), a);
                    }
                    acc[k] = a;
                }
            }
        }
        const float b1v = b1[0];
        float4 z4;
        z4.x = acc[0] + b1v; z4.y = acc[1] + b1v;
        z4.z = acc[2] + b1v; z4.w = acc[3] + b1v;
        *(float4*)(z + ebase) = z4;
        ss = (double)z4.x * z4.x + (double)z4.y * z4.y +
             (double)z4.z * z4.z + (double)z4.w * z4.w;
    }
    // fp64 tree reduce (bit-identical mapping to round 2); red overlays ws
    double* red = (double*)(smem + OFF_WS);
    red[t] = ss;
    __syncthreads();
#pragma unroll
    for (int off = 128; off > 0; off >>= 1) {
        if (t < off) red[t] += red[t + off];
        __syncthreads();
    }
    if (t == 0) partial[blockIdx.x] = red[0];
}

// ---------------------------------------------------------------------------
// Deterministic fp64 reduction of block partials -> max(||z||, 1e-12)
// ---------------------------------------------------------------------------
__global__ __launch_bounds__(256) void k_norm(const double* __restrict__ partial,
                                              double* __restrict__ nrm) {
    __shared__ double red[256];
    const int t = threadIdx.x;
    double s = 0.0;
    for (int i = t; i < NBLK2; i += 256) s += partial[i];
    red[t] = s;
    __syncthreads();
#pragma unroll
    for (int off = 128; off > 0; off >>= 1) {
        if (t < off) red[t] += red[t + off];
        __syncthreads();
    }
    if (t == 0) nrm[0] = fmax(sqrt(red[0]), 1e-12);
}

// ---------------------------------------------------------------------------
// Per-node fp64 softmax((z/||z|| + g)/T) + top-8 threshold mask (round-2 exact)
// ---------------------------------------------------------------------------
__global__ __launch_bounds__(256) void k_mask(const float* __restrict__ z,
                                              const float* __restrict__ gumbel,
                                              const double* __restrict__ nrm,
                                              const int* __restrict__ temperature,
                                              float* __restrict__ out) {
    const int n = blockIdx.x * 256 + threadIdx.x;
    if (n >= N_NODES) return;
    const double inv_nv = 1.0 / nrm[0];
    const double invT = 1.0 / (double)temperature[0];
    const float4* z4 = (const float4*)(z + (size_t)n * 16);
    const float4* g4 = (const float4*)(gumbel + (size_t)n * 16);
    double tl[16], y[16];
#pragma unroll
    for (int q = 0; q < 4; ++q) {
        float4 zv = z4[q];
        float4 gv = g4[q];
        tl[q * 4 + 0] = ((double)zv.x * inv_nv + (double)gv.x) * invT;
        tl[q * 4 + 1] = ((double)zv.y * inv_nv + (double)gv.y) * invT;
        tl[q * 4 + 2] = ((double)zv.z * inv_nv + (double)gv.z) * invT;
        tl[q * 4 + 3] = ((double)zv.w * inv_nv + (double)gv.w) * invT;
    }
    double m = tl[0];
#pragma unroll
    for (int i = 1; i < 16; ++i) m = fmax(m, tl[i]);
    double s = 0.0;
#pragma unroll
    for (int i = 0; i < 16; ++i) { y[i] = exp(tl[i] - m); s += y[i]; }
    const double inv_s = 1.0 / s;
#pragma unroll
    for (int i = 0; i < 16; ++i) y[i] *= inv_s;
    double thre = y[0];
#pragma unroll
    for (int i = 0; i < 16; ++i) {
        int c = 0, q = 0;
#pragma unroll
        for (int j = 0; j < 16; ++j) {
            c += (y[j] > y[i]) ? 1 : 0;
            q += (y[j] == y[i]) ? 1 : 0;
        }
        if (c <= 7 && 7 < c + q) thre = y[i];
    }
    float4* o4 = (float4*)(out + (size_t)n * 16);
#pragma unroll
    for (int qq = 0; qq < 4; ++qq) {
        float4 ov;
        ov.x = ((y[qq * 4 + 0] - thre + 1e-12) > 0.0) ? (float)y[qq * 4 + 0] : 0.f;
        ov.y = ((y[qq * 4 + 1] - thre + 1e-12) > 0.0) ? (float)y[qq * 4 + 1] : 0.f;
        ov.z = ((y[qq * 4 + 2] - thre + 1e-12) > 0.0) ? (float)y[qq * 4 + 2] : 0.f;
        ov.w = ((y[qq * 4 + 3] - thre + 1e-12) > 0.0) ? (float)y[qq * 4 + 3] : 0.f;
        o4[qq] = ov;
    }
}

// ---------------------------------------------------------------------------
extern "C" void kernel_launch(void* const* d_in, const int* in_sizes, int n_in,
                              void* d_out, int out_size, void* d_ws, size_t ws_size,
                              hipStream_t stream) {
    const float* feat    = (const float*)d_in[0];   // [N,64]
    const float* values  = (const float*)d_in[1];   // [E]
    const float* w0      = (const float*)d_in[2];   // [64,129]
    const float* b0      = (const float*)d_in[3];   // [64]
    const float* w1      = (const float*)d_in[4];   // [1,64]
    const float* b1      = (const float*)d_in[5];   // [1]
    const float* gumbel  = (const float*)d_in[6];   // [E]
    const int*   indices = (const int*)d_in[7];     // [2,E]
    const int*   temp    = (const int*)d_in[9];     // scalar
    float* out = (float*)d_out;

    // workspace: w0T 32KB | z 6.4MB | partial | nrm
    float*  w0T     = (float*)d_ws;
    float*  zbuf    = (float*)((char*)d_ws + 64 * 128 * 4);
    double* partial = (double*)((char*)d_ws + 64 * 128 * 4 + (size_t)N_EDGES * 4);
    double* nrm     = partial + NBLK2;

    k_prep <<<32, 256, 0, stream>>>(w0, w0T);
    k_fused<<<NBLK2, 256, 0, stream>>>(feat, values, indices, w0, w0T, b0, w1, b1,
                                       zbuf, partial);
    k_norm <<<1, 256, 0, stream>>>(partial, nrm);
    k_mask <<<(N_NODES + 255) / 256, 256, 0, stream>>>(zbuf, gumbel, nrm, temp, out);
}

// Round 5
// 80.195 us; speedup vs baseline: 1.3873x; 1.3873x over previous
//
#include <hip/hip_runtime.h>

#define N_NODES 100000
#define DEG 16
#define N_EDGES (N_NODES * DEG)
#define NT 64                              // nodes per k_edge block
#define NBLK2 ((N_NODES + NT - 1) / NT)    // 1563 edge blocks

// ---------------------------------------------------------------------------
// Prep: w0T[k][o] = A/B-split transpose of w0:
//   o <  64 : w0[o][k]        (A-part: weight for hidden o, input k)
//   o >= 64 : w0[o-64][64+k]  (B-part: weight for hidden o-64, input 64+k)
// 32 KB, L2-resident. Makes all later W staging coalesced.
// ---------------------------------------------------------------------------
__global__ __launch_bounds__(256) void k_prep(const float* __restrict__ w0,
                                              float* __restrict__ w0T) {
    int id = blockIdx.x * 256 + threadIdx.x;
    if (id < 64 * 128) {
        int k = id >> 7, o = id & 127;
        w0T[k * 128 + o] = (o < 64) ? w0[o * 129 + k]
                                    : w0[(o - 64) * 129 + 64 + k];
    }
}

// ---------------------------------------------------------------------------
// Kernel 1 (restructured for occupancy): per-node matvecs.
//   AB[n][0:64]   = W0[:, 0:64]  @ f[n] + b0     (A-part, b0 folded)
//   AB[n][64:128] = W0[:, 64:128]@ f[n]          (B-part)
// 64 nodes x 128 outs per 256-thread block; thread = 8 nodes x 4 outs.
// LDS = ws[32][128] (16 KB, K staged in 2 halves) + fs[64][64] (16 KB)
//     = 32 KB -> 4-5 blocks/CU (was 48 KB -> 2).  W staged from w0T
// (coalesced), fma chain k-ascending 0..63, bias after: bit-identical AB.
// ---------------------------------------------------------------------------
__global__ __launch_bounds__(256) void k_ab(const float* __restrict__ feat,
                                            const float* __restrict__ w0T,
                                            const float* __restrict__ b0,
                                            float* __restrict__ AB) {
    __shared__ float ws[32][128];
    __shared__ float fs[64][64];
    const int tid = threadIdx.x;
    const int n0 = blockIdx.x * 64;

    for (int idx = tid; idx < 1024; idx += 256) {      // feat tile: 64x64
        int flat = idx << 2;
        int nn = flat >> 6, k = flat & 63;
        int n = n0 + nn;
        float4 v = make_float4(0.f, 0.f, 0.f, 0.f);
        if (n < N_NODES) v = *(const float4*)(feat + (size_t)n * 64 + k);
        *(float4*)&fs[nn][k] = v;
    }
    for (int idx = tid; idx < 1024; idx += 256) {      // ws: K rows 0..31
        int k = idx >> 5, o4 = idx & 31;
        *(float4*)&ws[k][o4 * 4] = *(const float4*)&w0T[k * 128 + o4 * 4];
    }
    __syncthreads();

    const int to = tid & 31;   // out4-group: outs to*4..to*4+3
    const int tn = tid >> 5;   // node group: 8 nodes

#define FMA16(ACCR, F4)                                   \
    ACCR[0] = fmaf(F4.x, w40.x, ACCR[0]);                 \
    ACCR[1] = fmaf(F4.x, w40.y, ACCR[1]);                 \
    ACCR[2] = fmaf(F4.x, w40.z, ACCR[2]);                 \
    ACCR[3] = fmaf(F4.x, w40.w, ACCR[3]);                 \
    ACCR[0] = fmaf(F4.y, w41.x, ACCR[0]);                 \
    ACCR[1] = fmaf(F4.y, w41.y, ACCR[1]);                 \
    ACCR[2] = fmaf(F4.y, w41.z, ACCR[2]);                 \
    ACCR[3] = fmaf(F4.y, w41.w, ACCR[3]);                 \
    ACCR[0] = fmaf(F4.z, w42.x, ACCR[0]);                 \
    ACCR[1] = fmaf(F4.z, w42.y, ACCR[1]);                 \
    ACCR[2] = fmaf(F4.z, w42.z, ACCR[2]);                 \
    ACCR[3] = fmaf(F4.z, w42.w, ACCR[3]);                 \
    ACCR[0] = fmaf(F4.w, w43.x, ACCR[0]);                 \
    ACCR[1] = fmaf(F4.w, w43.y, ACCR[1]);                 \
    ACCR[2] = fmaf(F4.w, w43.z, ACCR[2]);                 \
    ACCR[3] = fmaf(F4.w, w43.w, ACCR[3]);

    float acc[8][4];
#pragma unroll
    for (int a = 0; a < 8; ++a) {
        acc[a][0] = 0.f; acc[a][1] = 0.f; acc[a][2] = 0.f; acc[a][3] = 0.f;
    }
#pragma unroll 1
    for (int h = 0; h < 2; ++h) {
        if (h == 1) {                                  // restage ws: K rows 32..63
            __syncthreads();
            for (int idx = tid; idx < 1024; idx += 256) {
                int k = idx >> 5, o4 = idx & 31;
                *(float4*)&ws[k][o4 * 4] =
                    *(const float4*)&w0T[(32 + k) * 128 + o4 * 4];
            }
            __syncthreads();
        }
#pragma unroll
        for (int k4 = 0; k4 < 8; ++k4) {
            const int kk = k4 * 4;
            float4 w40 = *(const float4*)&ws[kk + 0][to * 4];
            float4 w41 = *(const float4*)&ws[kk + 1][to * 4];
            float4 w42 = *(const float4*)&ws[kk + 2][to * 4];
            float4 w43 = *(const float4*)&ws[kk + 3][to * 4];
#pragma unroll
            for (int a = 0; a < 8; ++a) {
                float4 f4 = *(const float4*)&fs[tn * 8 + a][h * 32 + kk];
                FMA16(acc[a], f4)
            }
        }
    }
    float4 bb = make_float4(0.f, 0.f, 0.f, 0.f);
    if (to < 16) bb = *(const float4*)(b0 + to * 4);   // b0 folds into A-part only
#pragma unroll
    for (int a = 0; a < 8; ++a) {
        int n = n0 + tn * 8 + a;
        if (n < N_NODES) {
            float4 o4 = make_float4(acc[a][0] + bb.x, acc[a][1] + bb.y,
                                    acc[a][2] + bb.z, acc[a][3] + bb.w);
            *(float4*)(AB + (size_t)n * 128 + to * 4) = o4;
        }
    }
}

// ---------------------------------------------------------------------------
// Kernel 2 (round-2 verbatim): LDS-staged edge combine.
// Block = 64 nodes = 1024 edges; B-part rows (n0+1..n0+80)%N staged coalesced.
// ---------------------------------------------------------------------------
__global__ __launch_bounds__(256) void k_edge(const float* __restrict__ AB,
                                              const float* __restrict__ values,
                                              const int* __restrict__ indices,
                                              const float* __restrict__ w0,
                                              const float* __restrict__ w1,
                                              const float* __restrict__ b1,
                                              float* __restrict__ z,
                                              double* __restrict__ partial) {
    __shared__ float a_s[64][68];
    __shared__ float b_s[80][68];
    __shared__ float wv_s[64];
    __shared__ float w1_s[64];
    __shared__ double red[256];
    const int t = threadIdx.x;
    const int n0 = blockIdx.x * NT;
    const int nvalid = min(NT, N_NODES - n0);

    if (t < 64) {
        wv_s[t] = w0[t * 129 + 128];
        w1_s[t] = w1[t];
    }
    for (int idx = t; idx < 1024; idx += 256) {        // A: 64 rows x 16 float4
        int r = idx >> 4, k4 = idx & 15;
        float4 v = make_float4(0.f, 0.f, 0.f, 0.f);
        if (r < nvalid) v = *(const float4*)(AB + (size_t)(n0 + r) * 128 + k4 * 4);
        *(float4*)&a_s[r][k4 * 4] = v;
    }
    for (int idx = t; idx < 1280; idx += 256) {        // B: 80 rows x 16 float4
        int r = idx >> 4, k4 = idx & 15;
        int node = n0 + 1 + r;
        if (node >= N_NODES) node -= N_NODES;
        *(float4*)&b_s[r][k4 * 4] = *(const float4*)(AB + (size_t)node * 128 + 64 + k4 * 4);
    }
    __syncthreads();

    const int row = t >> 2;
    const bool ok = row < nvalid;
    double ss = 0.0;
    if (ok) {
        const int ebase = n0 * 16 + (t << 2);
        int4   c4 = *(const int4*)(indices + N_EDGES + ebase);
        float4 v4 = *(const float4*)(values + ebase);
        int   cols[4] = {c4.x, c4.y, c4.z, c4.w};
        float vv[4]   = {v4.x, v4.y, v4.z, v4.w};
        int   ii[4];
        bool  fb[4];
        bool  anyfb = false;
#pragma unroll
        for (int k = 0; k < 4; ++k) {
            int i = cols[k] - (n0 + 1);
            if (i < 0) i += N_NODES;
            fb[k] = (i >= 80);
            anyfb |= fb[k];
            ii[k] = fb[k] ? 0 : i;
        }
        float acc[4] = {0.f, 0.f, 0.f, 0.f};
#pragma unroll
        for (int q = 0; q < 16; ++q) {
            float4 a4  = *(const float4*)&a_s[row][q * 4];
            float4 wv4 = *(const float4*)&wv_s[q * 4];
            float4 w14 = *(const float4*)&w1_s[q * 4];
#pragma unroll
            for (int k = 0; k < 4; ++k) {
                float4 b4 = *(const float4*)&b_s[ii[k]][q * 4];
                float t0 = fmaf(wv4.x, vv[k], a4.x + b4.x);
                float t1 = fmaf(wv4.y, vv[k], a4.y + b4.y);
                float t2 = fmaf(wv4.z, vv[k], a4.z + b4.z);
                float t3 = fmaf(wv4.w, vv[k], a4.w + b4.w);
                acc[k] = fmaf(w14.x, fmaxf(t0, 0.f), acc[k]);
                acc[k] = fmaf(w14.y, fmaxf(t1, 0.f), acc[k]);
                acc[k] = fmaf(w14.z, fmaxf(t2, 0.f), acc[k]);
                acc[k] = fmaf(w14.w, fmaxf(t3, 0.f), acc[k]);
            }
        }
        if (anyfb) {            // never taken for this graph; correctness net
#pragma unroll
            for (int k = 0; k < 4; ++k) {
                if (fb[k]) {
                    const float* Bp = AB + (size_t)cols[k] * 128 + 64;
                    float a = 0.f;
                    for (int h = 0; h < 64; ++h) {
                        float th = fmaf(wv_s[h], vv[k], a_s[row][h] + Bp[h]);
                        a = fmaf(w1_s[h], fmaxf(th, 0.f), a);
                    }
                    acc[k] = a;
                }
            }
        }
        const float b1v = b1[0];
        float4 z4;
        z4.x = acc[0] + b1v; z4.y = acc[1] + b1v;
        z4.z = acc[2] + b1v; z4.w = acc[3] + b1v;
        *(float4*)(z + ebase) = z4;
        ss = (double)z4.x * z4.x + (double)z4.y * z4.y +
             (double)z4.z * z4.z + (double)z4.w * z4.w;
    }
    red[t] = ss;
    __syncthreads();
#pragma unroll
    for (int off = 128; off > 0; off >>= 1) {
        if (t < off) red[t] += red[t + off];
        __syncthreads();
    }
    if (t == 0) partial[blockIdx.x] = red[0];
}

// ---------------------------------------------------------------------------
// Deterministic fp64 reduction of block partials -> max(||z||, 1e-12)
// ---------------------------------------------------------------------------
__global__ __launch_bounds__(256) void k_norm(const double* __restrict__ partial,
                                              double* __restrict__ nrm) {
    __shared__ double red[256];
    const int t = threadIdx.x;
    double s = 0.0;
    for (int i = t; i < NBLK2; i += 256) s += partial[i];
    red[t] = s;
    __syncthreads();
#pragma unroll
    for (int off = 128; off > 0; off >>= 1) {
        if (t < off) red[t] += red[t + off];
        __syncthreads();
    }
    if (t == 0) nrm[0] = fmax(sqrt(red[0]), 1e-12);
}

// ---------------------------------------------------------------------------
// Per-node fp64 softmax((z/||z|| + g)/T) + top-8 threshold mask (round-2 exact)
// ---------------------------------------------------------------------------
__global__ __launch_bounds__(256) void k_mask(const float* __restrict__ z,
                                              const float* __restrict__ gumbel,
                                              const double* __restrict__ nrm,
                                              const int* __restrict__ temperature,
                                              float* __restrict__ out) {
    const int n = blockIdx.x * 256 + threadIdx.x;
    if (n >= N_NODES) return;
    const double inv_nv = 1.0 / nrm[0];
    const double invT = 1.0 / (double)temperature[0];
    const float4* z4 = (const float4*)(z + (size_t)n * 16);
    const float4* g4 = (const float4*)(gumbel + (size_t)n * 16);
    double tl[16], y[16];
#pragma unroll
    for (int q = 0; q < 4; ++q) {
        float4 zv = z4[q];
        float4 gv = g4[q];
        tl[q * 4 + 0] = ((double)zv.x * inv_nv + (double)gv.x) * invT;
        tl[q * 4 + 1] = ((double)zv.y * inv_nv + (double)gv.y) * invT;
        tl[q * 4 + 2] = ((double)zv.z * inv_nv + (double)gv.z) * invT;
        tl[q * 4 + 3] = ((double)zv.w * inv_nv + (double)gv.w) * invT;
    }
    double m = tl[0];
#pragma unroll
    for (int i = 1; i < 16; ++i) m = fmax(m, tl[i]);
    double s = 0.0;
#pragma unroll
    for (int i = 0; i < 16; ++i) { y[i] = exp(tl[i] - m); s += y[i]; }
    const double inv_s = 1.0 / s;
#pragma unroll
    for (int i = 0; i < 16; ++i) y[i] *= inv_s;
    double thre = y[0];
#pragma unroll
    for (int i = 0; i < 16; ++i) {
        int c = 0, q = 0;
#pragma unroll
        for (int j = 0; j < 16; ++j) {
            c += (y[j] > y[i]) ? 1 : 0;
            q += (y[j] == y[i]) ? 1 : 0;
        }
        if (c <= 7 && 7 < c + q) thre = y[i];
    }
    float4* o4 = (float4*)(out + (size_t)n * 16);
#pragma unroll
    for (int qq = 0; qq < 4; ++qq) {
        float4 ov;
        ov.x = ((y[qq * 4 + 0] - thre + 1e-12) > 0.0) ? (float)y[qq * 4 + 0] : 0.f;
        ov.y = ((y[qq * 4 + 1] - thre + 1e-12) > 0.0) ? (float)y[qq * 4 + 1] : 0.f;
        ov.z = ((y[qq * 4 + 2] - thre + 1e-12) > 0.0) ? (float)y[qq * 4 + 2] : 0.f;
        ov.w = ((y[qq * 4 + 3] - thre + 1e-12) > 0.0) ? (float)y[qq * 4 + 3] : 0.f;
        o4[qq] = ov;
    }
}

// ---------------------------------------------------------------------------
extern "C" void kernel_launch(void* const* d_in, const int* in_sizes, int n_in,
                              void* d_out, int out_size, void* d_ws, size_t ws_size,
                              hipStream_t stream) {
    const float* feat    = (const float*)d_in[0];   // [N,64]
    const float* values  = (const float*)d_in[1];   // [E]
    const float* w0      = (const float*)d_in[2];   // [64,129]
    const float* b0      = (const float*)d_in[3];   // [64]
    const float* w1      = (const float*)d_in[4];   // [1,64]
    const float* b1      = (const float*)d_in[5];   // [1]
    const float* gumbel  = (const float*)d_in[6];   // [E]
    const int*   indices = (const int*)d_in[7];     // [2,E]
    const int*   temp    = (const int*)d_in[9];     // scalar
    float* out = (float*)d_out;

    // workspace: w0T 32KB | AB 51.2MB | z 6.4MB | partial | nrm
    float*  w0T     = (float*)d_ws;
    float*  AB      = (float*)((char*)d_ws + 64 * 128 * 4);
    float*  zbuf    = (float*)((char*)d_ws + 64 * 128 * 4 + (size_t)N_NODES * 128 * 4);
    double* partial = (double*)((char*)d_ws + 64 * 128 * 4 + (size_t)N_NODES * 128 * 4
                                + (size_t)N_EDGES * 4);
    double* nrm     = partial + NBLK2;

    k_prep<<<32, 256, 0, stream>>>(w0, w0T);
    k_ab  <<<(N_NODES + 63) / 64, 256, 0, stream>>>(feat, w0T, b0, AB);
    k_edge<<<NBLK2, 256, 0, stream>>>(AB, values, indices, w0, w1, b1, zbuf, partial);
    k_norm<<<1, 256, 0, stream>>>(partial, nrm);
    k_mask<<<(N_NODES + 255) / 256, 256, 0, stream>>>(zbuf, gumbel, nrm, temp, out);
}

// Round 6
// 78.400 us; speedup vs baseline: 1.4191x; 1.0229x over previous
//
#include <hip/hip_runtime.h>

#define N_NODES 100000
#define DEG 16
#define N_EDGES (N_NODES * DEG)
#define NT 64                              // nodes per k_edge block / per k_ab tile
#define NBLK2 ((N_NODES + NT - 1) / NT)    // 1563 edge blocks
#define AB_TILES 2                         // node-tiles per k_ab block
#define NBLK_AB ((N_NODES + NT * AB_TILES - 1) / (NT * AB_TILES))   // 782

// ---------------------------------------------------------------------------
// Prep: w0T[k][o] = A/B-split transpose of w0:
//   o <  64 : w0[o][k]        (A-part: weight for hidden o, input k)
//   o >= 64 : w0[o-64][64+k]  (B-part: weight for hidden o-64, input 64+k)
// 32 KB, L2-resident. Makes all later W staging coalesced.
// ---------------------------------------------------------------------------
__global__ __launch_bounds__(256) void k_prep(const float* __restrict__ w0,
                                              float* __restrict__ w0T) {
    int id = blockIdx.x * 256 + threadIdx.x;
    if (id < 64 * 128) {
        int k = id >> 7, o = id & 127;
        w0T[k * 128 + o] = (o < 64) ? w0[o * 129 + k]
                                    : w0[(o - 64) * 129 + 64 + k];
    }
}

// ---------------------------------------------------------------------------
// Kernel 1 v4: per-node matvecs, 2 tiles of 64 nodes per block.
//   AB[n][0:64]   = W0[:, 0:64]  @ f[n] + b0     (A-part, b0 folded)
//   AB[n][64:128] = W0[:, 64:128]@ f[n]          (B-part)
// W (32 KB) staged ONCE per block (coalesced from w0T); per tile: stage
// feat 64x64, one barrier, compute, store. LDS 48 KB -> 3 blocks/CU; grid
// 782 ~= 3 per CU. fma chain k-ascending 0..63, bias after: AB bit-identical
// to round 2.
// ---------------------------------------------------------------------------
__global__ __launch_bounds__(256) void k_ab(const float* __restrict__ feat,
                                            const float* __restrict__ w0T,
                                            const float* __restrict__ b0,
                                            float* __restrict__ AB) {
    __shared__ float ws[64][128];   // 32 KB, whole W, staged once
    __shared__ float fs[64][64];    // 16 KB feature tile (per tile)
    const int tid = threadIdx.x;
    const int to = tid & 31;   // out4-group: outs to*4..to*4+3
    const int tn = tid >> 5;   // node group: 8 nodes

    for (int idx = tid; idx < 2048; idx += 256) {      // stage W once, coalesced
        int k = idx >> 5, o4 = idx & 31;
        *(float4*)&ws[k][o4 * 4] = *(const float4*)&w0T[k * 128 + o4 * 4];
    }
    float4 bb = make_float4(0.f, 0.f, 0.f, 0.f);
    if (to < 16) bb = *(const float4*)(b0 + to * 4);   // b0 folds into A-part only

#define FMA16(ACCR, F4)                                   \
    ACCR[0] = fmaf(F4.x, w40.x, ACCR[0]);                 \
    ACCR[1] = fmaf(F4.x, w40.y, ACCR[1]);                 \
    ACCR[2] = fmaf(F4.x, w40.z, ACCR[2]);                 \
    ACCR[3] = fmaf(F4.x, w40.w, ACCR[3]);                 \
    ACCR[0] = fmaf(F4.y, w41.x, ACCR[0]);                 \
    ACCR[1] = fmaf(F4.y, w41.y, ACCR[1]);                 \
    ACCR[2] = fmaf(F4.y, w41.z, ACCR[2]);                 \
    ACCR[3] = fmaf(F4.y, w41.w, ACCR[3]);                 \
    ACCR[0] = fmaf(F4.z, w42.x, ACCR[0]);                 \
    ACCR[1] = fmaf(F4.z, w42.y, ACCR[1]);                 \
    ACCR[2] = fmaf(F4.z, w42.z, ACCR[2]);                 \
    ACCR[3] = fmaf(F4.z, w42.w, ACCR[3]);                 \
    ACCR[0] = fmaf(F4.w, w43.x, ACCR[0]);                 \
    ACCR[1] = fmaf(F4.w, w43.y, ACCR[1]);                 \
    ACCR[2] = fmaf(F4.w, w43.z, ACCR[2]);                 \
    ACCR[3] = fmaf(F4.w, w43.w, ACCR[3]);

#pragma unroll 1
    for (int tile = 0; tile < AB_TILES; ++tile) {
        const int n0 = blockIdx.x * (NT * AB_TILES) + tile * NT;
        if (n0 >= N_NODES) break;                      // uniform across block
        __syncthreads();   // tile0: ws ready; tile>0: prev readers of fs done
        for (int idx = tid; idx < 1024; idx += 256) {  // stage feat tile 64x64
            int flat = idx << 2;
            int nn = flat >> 6, k = flat & 63;
            int n = n0 + nn;
            float4 v = make_float4(0.f, 0.f, 0.f, 0.f);
            if (n < N_NODES) v = *(const float4*)(feat + (size_t)n * 64 + k);
            *(float4*)&fs[nn][k] = v;
        }
        __syncthreads();

        float acc[8][4];
#pragma unroll
        for (int a = 0; a < 8; ++a) {
            acc[a][0] = 0.f; acc[a][1] = 0.f; acc[a][2] = 0.f; acc[a][3] = 0.f;
        }
#pragma unroll 4
        for (int k4 = 0; k4 < 16; ++k4) {
            const int kk = k4 * 4;
            float4 w40 = *(const float4*)&ws[kk + 0][to * 4];
            float4 w41 = *(const float4*)&ws[kk + 1][to * 4];
            float4 w42 = *(const float4*)&ws[kk + 2][to * 4];
            float4 w43 = *(const float4*)&ws[kk + 3][to * 4];
#pragma unroll
            for (int a = 0; a < 8; ++a) {
                float4 f4 = *(const float4*)&fs[tn * 8 + a][kk];
                FMA16(acc[a], f4)
            }
        }
#pragma unroll
        for (int a = 0; a < 8; ++a) {
            int n = n0 + tn * 8 + a;
            if (n < N_NODES) {
                float4 o4 = make_float4(acc[a][0] + bb.x, acc[a][1] + bb.y,
                                        acc[a][2] + bb.z, acc[a][3] + bb.w);
                *(float4*)(AB + (size_t)n * 128 + to * 4) = o4;
            }
        }
    }
}

// ---------------------------------------------------------------------------
// Kernel 2: LDS-staged edge combine (round-2 chain, bit-identical z).
// LDS trimmed to 38.8 KB (shuffle reduce) -> 4 blocks/CU.
// ---------------------------------------------------------------------------
__global__ __launch_bounds__(256) void k_edge(const float* __restrict__ AB,
                                              const float* __restrict__ values,
                                              const int* __restrict__ indices,
                                              const float* __restrict__ w0,
                                              const float* __restrict__ w1,
                                              const float* __restrict__ b1,
                                              float* __restrict__ z,
                                              double* __restrict__ partial) {
    __shared__ float a_s[64][68];
    __shared__ float b_s[80][68];
    __shared__ float wv_s[64];
    __shared__ float w1_s[64];
    __shared__ double redw[4];
    const int t = threadIdx.x;
    const int n0 = blockIdx.x * NT;
    const int nvalid = min(NT, N_NODES - n0);

    if (t < 64) {
        wv_s[t] = w0[t * 129 + 128];
        w1_s[t] = w1[t];
    }
    for (int idx = t; idx < 1024; idx += 256) {        // A: 64 rows x 16 float4
        int r = idx >> 4, k4 = idx & 15;
        float4 v = make_float4(0.f, 0.f, 0.f, 0.f);
        if (r < nvalid) v = *(const float4*)(AB + (size_t)(n0 + r) * 128 + k4 * 4);
        *(float4*)&a_s[r][k4 * 4] = v;
    }
    for (int idx = t; idx < 1280; idx += 256) {        // B: 80 rows x 16 float4
        int r = idx >> 4, k4 = idx & 15;
        int node = n0 + 1 + r;
        if (node >= N_NODES) node -= N_NODES;
        *(float4*)&b_s[r][k4 * 4] = *(const float4*)(AB + (size_t)node * 128 + 64 + k4 * 4);
    }
    __syncthreads();

    const int row = t >> 2;
    const bool ok = row < nvalid;
    double ss = 0.0;
    if (ok) {
        const int ebase = n0 * 16 + (t << 2);
        int4   c4 = *(const int4*)(indices + N_EDGES + ebase);
        float4 v4 = *(const float4*)(values + ebase);
        int   cols[4] = {c4.x, c4.y, c4.z, c4.w};
        float vv[4]   = {v4.x, v4.y, v4.z, v4.w};
        int   ii[4];
        bool  fb[4];
        bool  anyfb = false;
#pragma unroll
        for (int k = 0; k < 4; ++k) {
            int i = cols[k] - (n0 + 1);
            if (i < 0) i += N_NODES;
            fb[k] = (i >= 80);
            anyfb |= fb[k];
            ii[k] = fb[k] ? 0 : i;
        }
        float acc[4] = {0.f, 0.f, 0.f, 0.f};
#pragma unroll
        for (int q = 0; q < 16; ++q) {
            float4 a4  = *(const float4*)&a_s[row][q * 4];
            float4 wv4 = *(const float4*)&wv_s[q * 4];
            float4 w14 = *(const float4*)&w1_s[q * 4];
#pragma unroll
            for (int k = 0; k < 4; ++k) {
                float4 b4 = *(const float4*)&b_s[ii[k]][q * 4];
                float t0 = fmaf(wv4.x, vv[k], a4.x + b4.x);
                float t1 = fmaf(wv4.y, vv[k], a4.y + b4.y);
                float t2 = fmaf(wv4.z, vv[k], a4.z + b4.z);
                float t3 = fmaf(wv4.w, vv[k], a4.w + b4.w);
                acc[k] = fmaf(w14.x, fmaxf(t0, 0.f), acc[k]);
                acc[k] = fmaf(w14.y, fmaxf(t1, 0.f), acc[k]);
                acc[k] = fmaf(w14.z, fmaxf(t2, 0.f), acc[k]);
                acc[k] = fmaf(w14.w, fmaxf(t3, 0.f), acc[k]);
            }
        }
        if (anyfb) {            // never taken for this graph; correctness net
#pragma unroll
            for (int k = 0; k < 4; ++k) {
                if (fb[k]) {
                    const float* Bp = AB + (size_t)cols[k] * 128 + 64;
                    float a = 0.f;
                    for (int h = 0; h < 64; ++h) {
                        float th = fmaf(wv_s[h], vv[k], a_s[row][h] + Bp[h]);
                        a = fmaf(w1_s[h], fmaxf(th, 0.f), a);
                    }
                    acc[k] = a;
                }
            }
        }
        const float b1v = b1[0];
        float4 z4;
        z4.x = acc[0] + b1v; z4.y = acc[1] + b1v;
        z4.z = acc[2] + b1v; z4.w = acc[3] + b1v;
        *(float4*)(z + ebase) = z4;
        ss = (double)z4.x * z4.x + (double)z4.y * z4.y +
             (double)z4.z * z4.z + (double)z4.w * z4.w;
    }
    // deterministic wave shuffle reduce (fp64), then 4 partials -> block sum
#pragma unroll
    for (int off = 32; off > 0; off >>= 1) ss += __shfl_down(ss, off, 64);
    if ((t & 63) == 0) redw[t >> 6] = ss;
    __syncthreads();
    if (t == 0) partial[blockIdx.x] = (redw[0] + redw[1]) + (redw[2] + redw[3]);
}

// ---------------------------------------------------------------------------
// Deterministic fp64 reduction of block partials -> max(||z||, 1e-12)
// ---------------------------------------------------------------------------
__global__ __launch_bounds__(256) void k_norm(const double* __restrict__ partial,
                                              double* __restrict__ nrm) {
    __shared__ double red[256];
    const int t = threadIdx.x;
    double s = 0.0;
    for (int i = t; i < NBLK2; i += 256) s += partial[i];
    red[t] = s;
    __syncthreads();
#pragma unroll
    for (int off = 128; off > 0; off >>= 1) {
        if (t < off) red[t] += red[t + off];
        __syncthreads();
    }
    if (t == 0) nrm[0] = fmax(sqrt(red[0]), 1e-12);
}

// ---------------------------------------------------------------------------
// Per-node fp64 softmax((z/||z|| + g)/T) + top-8 threshold mask (round-2 exact)
// ---------------------------------------------------------------------------
__global__ __launch_bounds__(256) void k_mask(const float* __restrict__ z,
                                              const float* __restrict__ gumbel,
                                              const double* __restrict__ nrm,
                                              const int* __restrict__ temperature,
                                              float* __restrict__ out) {
    const int n = blockIdx.x * 256 + threadIdx.x;
    if (n >= N_NODES) return;
    const double inv_nv = 1.0 / nrm[0];
    const double invT = 1.0 / (double)temperature[0];
    const float4* z4 = (const float4*)(z + (size_t)n * 16);
    const float4* g4 = (const float4*)(gumbel + (size_t)n * 16);
    double tl[16], y[16];
#pragma unroll
    for (int q = 0; q < 4; ++q) {
        float4 zv = z4[q];
        float4 gv = g4[q];
        tl[q * 4 + 0] = ((double)zv.x * inv_nv + (double)gv.x) * invT;
        tl[q * 4 + 1] = ((double)zv.y * inv_nv + (double)gv.y) * invT;
        tl[q * 4 + 2] = ((double)zv.z * inv_nv + (double)gv.z) * invT;
        tl[q * 4 + 3] = ((double)zv.w * inv_nv + (double)gv.w) * invT;
    }
    double m = tl[0];
#pragma unroll
    for (int i = 1; i < 16; ++i) m = fmax(m, tl[i]);
    double s = 0.0;
#pragma unroll
    for (int i = 0; i < 16; ++i) { y[i] = exp(tl[i] - m); s += y[i]; }
    const double inv_s = 1.0 / s;
#pragma unroll
    for (int i = 0; i < 16; ++i) y[i] *= inv_s;
    double thre = y[0];
#pragma unroll
    for (int i = 0; i < 16; ++i) {
        int c = 0, q = 0;
#pragma unroll
        for (int j = 0; j < 16; ++j) {
            c += (y[j] > y[i]) ? 1 : 0;
            q += (y[j] == y[i]) ? 1 : 0;
        }
        if (c <= 7 && 7 < c + q) thre = y[i];
    }
    float4* o4 = (float4*)(out + (size_t)n * 16);
#pragma unroll
    for (int qq = 0; qq < 4; ++qq) {
        float4 ov;
        ov.x = ((y[qq * 4 + 0] - thre + 1e-12) > 0.0) ? (float)y[qq * 4 + 0] : 0.f;
        ov.y = ((y[qq * 4 + 1] - thre + 1e-12) > 0.0) ? (float)y[qq * 4 + 1] : 0.f;
        ov.z = ((y[qq * 4 + 2] - thre + 1e-12) > 0.0) ? (float)y[qq * 4 + 2] : 0.f;
        ov.w = ((y[qq * 4 + 3] - thre + 1e-12) > 0.0) ? (float)y[qq * 4 + 3] : 0.f;
        o4[qq] = ov;
    }
}

// ---------------------------------------------------------------------------
extern "C" void kernel_launch(void* const* d_in, const int* in_sizes, int n_in,
                              void* d_out, int out_size, void* d_ws, size_t ws_size,
                              hipStream_t stream) {
    const float* feat    = (const float*)d_in[0];   // [N,64]
    const float* values  = (const float*)d_in[1];   // [E]
    const float* w0      = (const float*)d_in[2];   // [64,129]
    const float* b0      = (const float*)d_in[3];   // [64]
    const float* w1      = (const float*)d_in[4];   // [1,64]
    const float* b1      = (const float*)d_in[5];   // [1]
    const float* gumbel  = (const float*)d_in[6];   // [E]
    const int*   indices = (const int*)d_in[7];     // [2,E]
    const int*   temp    = (const int*)d_in[9];     // scalar
    float* out = (float*)d_out;

    // workspace: w0T 32KB | AB 51.2MB | z 6.4MB | partial | nrm
    float*  w0T     = (float*)d_ws;
    float*  AB      = (float*)((char*)d_ws + 64 * 128 * 4);
    float*  zbuf    = (float*)((char*)d_ws + 64 * 128 * 4 + (size_t)N_NODES * 128 * 4);
    double* partial = (double*)((char*)d_ws + 64 * 128 * 4 + (size_t)N_NODES * 128 * 4
                                + (size_t)N_EDGES * 4);
    double* nrm     = partial + NBLK2;

    k_prep<<<32, 256, 0, stream>>>(w0, w0T);
    k_ab  <<<NBLK_AB, 256, 0, stream>>>(feat, w0T, b0, AB);
    k_edge<<<NBLK2, 256, 0, stream>>>(AB, values, indices, w0, w1, b1, zbuf, partial);
    k_norm<<<1, 256, 0, stream>>>(partial, nrm);
    k_mask<<<(N_NODES + 255) / 256, 256, 0, stream>>>(zbuf, gumbel, nrm, temp, out);
}